// Round 13
// baseline (274.785 us; speedup 1.0000x reference)
//
#include <hip/hip_runtime.h>

#define N_NODES 100000
#define N_EDGES 1600000
#define NBUCK   ((N_NODES + 127) / 128)   // 782 buckets of 128 rows
#define BCAP    4096                      // fixed bucket capacity (mean 2048, std ~45)
// IN_DIM=512, HID_DIM=128, OUT_DIM=64

typedef __attribute__((ext_vector_type(8))) short bf16x8;
typedef __attribute__((ext_vector_type(4))) float f32x4;

__device__ __forceinline__ unsigned short f2bf(float f) {
    unsigned int u = __builtin_bit_cast(unsigned int, f);
    u = (u + 0x7FFFu + ((u >> 16) & 1u)) >> 16;   // RNE
    return (unsigned short)u;
}
__device__ __forceinline__ float bfu2f(unsigned short u) {
    return __builtin_bit_cast(float, (unsigned int)u << 16);
}
__device__ __forceinline__ bf16x8 pack8(float4 a, float4 b) {
    bf16x8 r;
    r[0] = (short)f2bf(a.x); r[1] = (short)f2bf(a.y);
    r[2] = (short)f2bf(a.z); r[3] = (short)f2bf(a.w);
    r[4] = (short)f2bf(b.x); r[5] = (short)f2bf(b.y);
    r[6] = (short)f2bf(b.z); r[7] = (short)f2bf(b.w);
    return r;
}

// Async global->LDS DMA, 16B per lane (dest = wave-uniform base + lane*16).
__device__ __forceinline__ void gl_lds16(const void* g, void* s) {
    __builtin_amdgcn_global_load_lds(
        (const __attribute__((address_space(1))) void*)g,
        (__attribute__((address_space(3))) void*)s, 16, 0, 0);
}

// ---------------------------------------------------------------------------
// prep: W0->W0t bf16 transposed, W1->W1t bf16 transposed,
// bcursor[b] = b*BCAP (fixed bucket bases).
// ---------------------------------------------------------------------------
__global__ __launch_bounds__(256) void prep_kernel(const float* __restrict__ W0,
                                                   const float* __restrict__ W1,
                                                   unsigned short* __restrict__ W0t,
                                                   unsigned short* __restrict__ W1t,
                                                   int* __restrict__ bcursor) {
    const int i = blockIdx.x * 256 + threadIdx.x;
    if (i < 512 * 128) {
        const int k = i / 128, c = i % 128;
        W0t[c * 512 + k] = f2bf(W0[i]);
    }
    const int j = i - 512 * 128;
    if (j >= 0 && j < 128 * 64) {
        const int k = j / 64, c = j % 64;
        W1t[c * 128 + k] = f2bf(W1[j]);
    }
    const int z = i - (512 * 128 + 128 * 64);
    if (z >= 0 && z < NBUCK) bcursor[z] = z * BCAP;
}

// ---------------------------------------------------------------------------
// GEMM1 (global_load_lds async staging): sup0_bf16[N,128] = A_f32[N,512] @ W0.
// Tile 64x128, 4 waves (2m x 2n), BK=32, 16 k-steps, double-buffered LDS.
// A staged fp32 as [kc(8)][row(64)] 16B-slots; B bf16 as [kc(4)][col(128)]
// slots -> fragment reads are CONFLICT-FREE (16 lanes walk consecutive slots)
// with LINEAR DMA destinations (no swizzle needed). stage(t+1) is issued
// before compute(t); __syncthreads()'s vmcnt drain lands after the compute
// phase (m97 structure). fp32->bf16 convert fused into fragment read.
// ---------------------------------------------------------------------------
__global__ __launch_bounds__(256) void gemm1_kernel(const float* __restrict__ A,
                                                    const unsigned short* __restrict__ Wt,
                                                    unsigned short* __restrict__ C, int N) {
    __shared__ __align__(16) float4 AsF4[2][8 * 64];   // 2 x 8KB
    __shared__ __align__(16) uint4  Bs4[2][4 * 128];   // 2 x 8KB

    const int tid  = threadIdx.x;
    const int lane = tid & 63;
    const int w    = tid >> 6;       // wave id 0..3
    const int wm   = w >> 1;
    const int wn   = w & 1;
    const int brow = blockIdx.x * 64;

    // staging sources (per lane). A: chunk c=2w,2w+1 covers kc pair; row=lane.
    const int grow = min(brow + lane, N - 1);   // clamp: OOB rows never written out
    const float* asrc = A + (size_t)grow * 512;
    // B: chunk c covers kc=c>>1 (=w), col-half=c&1; col=(c&1)*64+lane.
    const unsigned short* bsrc0 = Wt + (size_t)(lane)      * 512 + w * 8;  // c=2w   (cols 0..63)
    const unsigned short* bsrc1 = Wt + (size_t)(64 + lane) * 512 + w * 8;  // c=2w+1 (cols 64..127)

    auto stage = [&](int t, int buf) {
        const int koA = t * 32;                       // floats
        gl_lds16(asrc + koA + (2 * w)     * 4, &AsF4[buf][(2 * w)     * 64]);
        gl_lds16(asrc + koA + (2 * w + 1) * 4, &AsF4[buf][(2 * w + 1) * 64]);
        gl_lds16(bsrc0 + t * 32,               &Bs4[buf][(2 * w)     * 64]);
        gl_lds16(bsrc1 + t * 32,               &Bs4[buf][(2 * w + 1) * 64]);
    };

    f32x4 acc[2][4];
#pragma unroll
    for (int m = 0; m < 2; ++m)
#pragma unroll
        for (int n = 0; n < 4; ++n) acc[m][n] = (f32x4){0.f, 0.f, 0.f, 0.f};

    const int kq  = lane >> 4;        // 0..3
    const int rlo = lane & 15;

    auto step = [&](int buf) {
        bf16x8 af[2];
#pragma unroll
        for (int m = 0; m < 2; ++m) {
            const int row = wm * 32 + m * 16 + rlo;
            const float4 lo = AsF4[buf][(kq * 2 + 0) * 64 + row];
            const float4 hi = AsF4[buf][(kq * 2 + 1) * 64 + row];
            af[m] = pack8(lo, hi);
        }
        bf16x8 bfr[4];
#pragma unroll
        for (int n = 0; n < 4; ++n) {
            const int col = wn * 64 + n * 16 + rlo;
            const uint4 u = Bs4[buf][kq * 128 + col];
            bfr[n] = __builtin_bit_cast(bf16x8, u);
        }
#pragma unroll
        for (int m = 0; m < 2; ++m)
#pragma unroll
            for (int n = 0; n < 4; ++n)
                acc[m][n] = __builtin_amdgcn_mfma_f32_16x16x32_bf16(af[m], bfr[n], acc[m][n], 0, 0, 0);
    };

    stage(0, 0);
    __syncthreads();

#pragma unroll
    for (int t = 0; t < 16; ++t) {
        if (t + 1 < 16) stage(t + 1, (t + 1) & 1);   // DMA into idle buffer
        step(t & 1);                                  // compute current buffer
        __syncthreads();                              // drain vmcnt after compute
    }

    // epilogue: C/D layout col=lane&15, row=(lane>>4)*4+j
    const int rb = brow + wm * 32 + kq * 4;
    const int cb = wn * 64 + rlo;
#pragma unroll
    for (int m = 0; m < 2; ++m)
#pragma unroll
        for (int n = 0; n < 4; ++n)
#pragma unroll
            for (int j = 0; j < 4; ++j) {
                const int r = rb + m * 16 + j;
                if (r < N) C[(size_t)r * 128 + cb + n * 16] = f2bf(acc[m][n][j]);
            }
}

// ---------------------------------------------------------------------------
// LDS-free GEMM2: sup1_bf16[N,64] = h_bf16[N,128] @ W1 (Wt[64][128] bf16).
// ---------------------------------------------------------------------------
__global__ __launch_bounds__(256) void gemm2_kernel(const unsigned short* __restrict__ Hb,
                                                    const unsigned short* __restrict__ Wt,
                                                    unsigned short* __restrict__ C) {
    const int gw = (blockIdx.x * 256 + threadIdx.x) >> 6;
    if (gw >= N_NODES / 16) return;
    const int lane = threadIdx.x & 63;
    const int rlo = lane & 15, khi = lane >> 4;
    const int rb = gw * 16;

    const unsigned short* wp = Wt + (size_t)rlo * 128 + khi * 8;
    bf16x8 b[4][4];
#pragma unroll
    for (int n = 0; n < 4; ++n)
#pragma unroll
        for (int t = 0; t < 4; ++t)
            b[n][t] = *reinterpret_cast<const bf16x8*>(wp + (size_t)n * 16 * 128 + t * 32);

    f32x4 acc[4];
#pragma unroll
    for (int n = 0; n < 4; ++n) acc[n] = (f32x4){0.f, 0.f, 0.f, 0.f};

    const unsigned short* hp = Hb + (size_t)(rb + rlo) * 128 + khi * 8;
#pragma unroll
    for (int t = 0; t < 4; ++t) {
        const bf16x8 af = *reinterpret_cast<const bf16x8*>(hp + t * 32);
#pragma unroll
        for (int n = 0; n < 4; ++n)
            acc[n] = __builtin_amdgcn_mfma_f32_16x16x32_bf16(af, b[n][t], acc[n], 0, 0, 0);
    }

#pragma unroll
    for (int n = 0; n < 4; ++n)
#pragma unroll
        for (int j = 0; j < 4; ++j)
            C[(size_t)(rb + khi * 4 + j) * 64 + n * 16 + rlo] = f2bf(acc[n][j]);
}

// ---------------------------------------------------------------------------
// Bucket append (block-aggregated): LDS histogram -> one global atomic per
// (block, nonzero bucket) -> append into fixed region [b*BCAP ...).
// ---------------------------------------------------------------------------
#define SCAT_CH 4096
__global__ __launch_bounds__(256) void scatter_bucket_kernel(const int* __restrict__ rows,
                                                             const int* __restrict__ cols,
                                                             const float* __restrict__ vals,
                                                             int* __restrict__ bcursor,
                                                             int2* __restrict__ tmp) {
    __shared__ int hist[NBUCK];   // counts, then global-base cursors
    const int tid = threadIdx.x;
    const int e0  = blockIdx.x * SCAT_CH;

    for (int b = tid; b < NBUCK; b += 256) hist[b] = 0;
    __syncthreads();

#pragma unroll
    for (int i = 0; i < SCAT_CH / 256; ++i) {
        const int e = e0 + i * 256 + tid;
        if (e < N_EDGES) atomicAdd(&hist[rows[e] >> 7], 1);
    }
    __syncthreads();

    for (int b = tid; b < NBUCK; b += 256) {
        const int hcnt = hist[b];
        hist[b] = (hcnt > 0) ? atomicAdd(&bcursor[b], hcnt) : 0;
    }
    __syncthreads();

#pragma unroll
    for (int i = 0; i < SCAT_CH / 256; ++i) {
        const int e = e0 + i * 256 + tid;
        if (e < N_EDGES) {
            const int r   = rows[e];
            const int pos = atomicAdd(&hist[r >> 7], 1);
            tmp[pos] = make_int2(cols[e] | ((r & 127) << 17), __float_as_int(vals[e]));
        }
    }
}

// ---------------------------------------------------------------------------
// bucket_csr: one block per bucket. LDS int histogram, thread-0 scan,
// row_range emit, row-sort bucket into meta via LDS int cursors.
// ---------------------------------------------------------------------------
__global__ __launch_bounds__(256) void bucket_csr_kernel(const int* __restrict__ bcursor,
                                                         const int2* __restrict__ tmp,
                                                         int2* __restrict__ meta,
                                                         int2* __restrict__ row_range) {
    __shared__ int cnt_sh[128];
    __shared__ int startsh[128];
    __shared__ int cur[128];
    const int b   = blockIdx.x;
    const int tid = threadIdx.x;
    const int base = b * BCAP;
    const int cnt  = bcursor[b] - base;

    if (tid < 128) cnt_sh[tid] = 0;
    __syncthreads();

    for (int j = tid; j < cnt; j += 256)
        atomicAdd(&cnt_sh[((unsigned int)tmp[base + j].x) >> 17], 1);
    __syncthreads();

    if (tid == 0) {
        int a = base;
        for (int i = 0; i < 128; ++i) { startsh[i] = a; a += cnt_sh[i]; }
    }
    __syncthreads();

    if (tid < 128) {
        cur[tid] = startsh[tid];
        const int row = (b << 7) + tid;
        if (row < N_NODES)
            row_range[row] = make_int2(startsh[tid], startsh[tid] + cnt_sh[tid]);
    }
    __syncthreads();

    for (int j = tid; j < cnt; j += 256) {
        const int2 w  = tmp[base + j];
        const int  rl = ((unsigned int)w.x) >> 17;
        const int  pos = atomicAdd(&cur[rl], 1);
        meta[pos] = make_int2(w.x & 0x1FFFF, w.y);
    }
}

// ---------------------------------------------------------------------------
// Atomic-free SpMM, one wave per row, NG edge-parallel groups, UN=2 unroll.
// ---------------------------------------------------------------------------
template<int DIM, bool RELU_BF16_OUT>
__global__ __launch_bounds__(256) void spmm_kernel(const int2* __restrict__ row_range,
                                                   const int2* __restrict__ meta,
                                                   const unsigned short* __restrict__ sup,
                                                   const float* __restrict__ bias,
                                                   void* __restrict__ aggv) {
    const int wv = (blockIdx.x * 256 + threadIdx.x) >> 6;  // row id
    if (wv >= N_NODES) return;
    const int lane = threadIdx.x & 63;

    constexpr int GL = DIM / 8;              // lanes per group (16 / 8)
    constexpr int NG = 64 / GL;              // edge-parallel groups (4 / 8)
    constexpr int UN = 2;                    // unroll depth
    const int grp = lane / GL;
    const int sub = lane % GL;

    const int2 rr = row_range[wv];
    const int start = rr.x, end = rr.y;

    float a[8] = {0.f, 0.f, 0.f, 0.f, 0.f, 0.f, 0.f, 0.f};

    int j = start + grp;
    while (j + (UN - 1) * NG < end) {
        int2 e[UN];
#pragma unroll
        for (int u = 0; u < UN; ++u) e[u] = meta[j + u * NG];
        bf16x8 s[UN];
#pragma unroll
        for (int u = 0; u < UN; ++u)
            s[u] = *reinterpret_cast<const bf16x8*>(sup + (size_t)e[u].x * DIM + sub * 8);
#pragma unroll
        for (int u = 0; u < UN; ++u) {
            const float v = __int_as_float(e[u].y);
#pragma unroll
            for (int d = 0; d < 8; ++d)
                a[d] = fmaf(v, bfu2f((unsigned short)s[u][d]), a[d]);
        }
        j += UN * NG;
    }
    for (; j < end; j += NG) {
        const int2 e = meta[j];
        const bf16x8 s = *reinterpret_cast<const bf16x8*>(sup + (size_t)e.x * DIM + sub * 8);
        const float v = __int_as_float(e.y);
#pragma unroll
        for (int d = 0; d < 8; ++d)
            a[d] = fmaf(v, bfu2f((unsigned short)s[d]), a[d]);
    }

#pragma unroll
    for (int d = 0; d < 8; ++d) {
        if (GL == 8) a[d] += __shfl_xor(a[d], 8);
        a[d] += __shfl_xor(a[d], 16);
        a[d] += __shfl_xor(a[d], 32);
    }

    if (lane < GL) {
        const float4 b0 = *reinterpret_cast<const float4*>(bias + sub * 8);
        const float4 b1 = *reinterpret_cast<const float4*>(bias + sub * 8 + 4);
        float o[8];
        o[0] = a[0] + b0.x; o[1] = a[1] + b0.y; o[2] = a[2] + b0.z; o[3] = a[3] + b0.w;
        o[4] = a[4] + b1.x; o[5] = a[5] + b1.y; o[6] = a[6] + b1.z; o[7] = a[7] + b1.w;
        if (RELU_BF16_OUT) {
            unsigned short* h = (unsigned short*)aggv;
            bf16x8 r;
#pragma unroll
            for (int d = 0; d < 8; ++d) r[d] = (short)f2bf(fmaxf(o[d], 0.f));
            *reinterpret_cast<bf16x8*>(h + (size_t)wv * DIM + sub * 8) = r;
        } else {
            float* og = (float*)aggv;
            float* dst = og + (size_t)wv * DIM + sub * 8;
            *reinterpret_cast<float4*>(dst)     = make_float4(o[0], o[1], o[2], o[3]);
            *reinterpret_cast<float4*>(dst + 4) = make_float4(o[4], o[5], o[6], o[7]);
        }
    }
}

// ---------------------------------------------------------------------------
extern "C" void kernel_launch(void* const* d_in, const int* in_sizes, int n_in,
                              void* d_out, int out_size, void* d_ws, size_t ws_size,
                              hipStream_t stream) {
    const float* x    = (const float*)d_in[0];
    const int*   rows = (const int*)d_in[1];
    const int*   cols = (const int*)d_in[2];
    const float* vals = (const float*)d_in[3];
    const float* W0   = (const float*)d_in[4];
    const float* b0   = (const float*)d_in[5];
    const float* W1   = (const float*)d_in[6];
    const float* b1   = (const float*)d_in[7];
    float*       out  = (float*)d_out;

    // Workspace carve (all chunks 16B-multiple)
    char* p = (char*)d_ws;
    unsigned short* sup0 = (unsigned short*)p;  p += (size_t)N_NODES * 128 * 2;  // 25.6 MB
    unsigned short* h    = (unsigned short*)p;  p += (size_t)N_NODES * 128 * 2;  // 25.6 MB
    unsigned short* sup1 = (unsigned short*)p;  p += (size_t)N_NODES * 64 * 2;   // 12.8 MB
    unsigned short* W0t  = (unsigned short*)p;  p += (size_t)512 * 128 * 2;
    unsigned short* W1t  = (unsigned short*)p;  p += (size_t)128 * 64 * 2;
    int*   bcursor  = (int*)p;                  p += (size_t)((NBUCK + 3) / 4) * 16;
    int2*  row_range= (int2*)p;                 p += (size_t)N_NODES * 8;        // 0.8 MB
    int2*  tmp      = (int2*)p;                 p += (size_t)NBUCK * BCAP * 8;   // 25.6 MB
    int2*  meta     = (int2*)p;                 p += (size_t)NBUCK * BCAP * 8;   // 25.6 MB

    const int prep_blocks = (512 * 128 + 128 * 64 + NBUCK + 255) / 256;  // 292
    const int scat_blocks = (N_EDGES + SCAT_CH - 1) / SCAT_CH;           // 391
    const int gemm_blocks = (N_NODES + 63) / 64;                         // 1563
    const int gem2_blocks = (N_NODES / 16 + 3) / 4;                      // 1563
    const int spmm_blocks = (N_NODES * 64 + 255) / 256;                  // 25000

    // ---- prep (W converts + bucket cursor init) ----
    prep_kernel<<<prep_blocks, 256, 0, stream>>>(W0, W1, W0t, W1t, bcursor);

    // ---- edge reorg: bucket append + per-bucket CSR finish ----
    scatter_bucket_kernel<<<scat_blocks, 256, 0, stream>>>(rows, cols, vals, bcursor, tmp);
    bucket_csr_kernel<<<NBUCK, 256, 0, stream>>>(bcursor, tmp, meta, row_range);

    // ---- Layer 0 ----
    gemm1_kernel<<<gemm_blocks, 256, 0, stream>>>(x, W0t, sup0, N_NODES);
    spmm_kernel<128, true><<<spmm_blocks, 256, 0, stream>>>(row_range, meta, sup0, b0, h);

    // ---- Layer 1 ----
    gemm2_kernel<<<gem2_blocks, 256, 0, stream>>>(h, W1t, sup1);
    spmm_kernel<64, false><<<spmm_blocks, 256, 0, stream>>>(row_range, meta, sup1, b1, out);
}

// Round 14
// 224.401 us; speedup vs baseline: 1.2245x; 1.2245x over previous
//
#include <hip/hip_runtime.h>

#define N_NODES 100000
#define N_EDGES 1600000
#define NBUCK   ((N_NODES + 127) / 128)   // 782 buckets of 128 rows
#define BCAP    4096                      // fixed bucket capacity (mean 2048, std ~45)
// IN_DIM=512, HID_DIM=128, OUT_DIM=64

typedef __attribute__((ext_vector_type(8))) short bf16x8;
typedef __attribute__((ext_vector_type(4))) float f32x4;

__device__ __forceinline__ unsigned short f2bf(float f) {
    unsigned int u = __builtin_bit_cast(unsigned int, f);
    u = (u + 0x7FFFu + ((u >> 16) & 1u)) >> 16;   // RNE
    return (unsigned short)u;
}
__device__ __forceinline__ float bfu2f(unsigned short u) {
    return __builtin_bit_cast(float, (unsigned int)u << 16);
}
__device__ __forceinline__ uint2 packbf4(float4 v) {
    uint2 p;
    p.x = (unsigned int)f2bf(v.x) | ((unsigned int)f2bf(v.y) << 16);
    p.y = (unsigned int)f2bf(v.z) | ((unsigned int)f2bf(v.w) << 16);
    return p;
}

// Raw barrier: waits LDS ops only — global prefetch loads stay in flight.
__device__ __forceinline__ void block_barrier() {
    asm volatile("s_waitcnt lgkmcnt(0)" ::: "memory");
    __builtin_amdgcn_sched_barrier(0);
    __builtin_amdgcn_s_barrier();
    __builtin_amdgcn_sched_barrier(0);
}

// ---------------------------------------------------------------------------
// prep: W0->W0t bf16 transposed, W1->W1t bf16 transposed,
// bcursor[b] = b*BCAP (fixed bucket bases).
// ---------------------------------------------------------------------------
__global__ __launch_bounds__(256) void prep_kernel(const float* __restrict__ W0,
                                                   const float* __restrict__ W1,
                                                   unsigned short* __restrict__ W0t,
                                                   unsigned short* __restrict__ W1t,
                                                   int* __restrict__ bcursor) {
    const int i = blockIdx.x * 256 + threadIdx.x;
    if (i < 512 * 128) {
        const int k = i / 128, c = i % 128;
        W0t[c * 512 + k] = f2bf(W0[i]);
    }
    const int j = i - 512 * 128;
    if (j >= 0 && j < 128 * 64) {
        const int k = j / 64, c = j % 64;
        W1t[c * 128 + k] = f2bf(W1[j]);
    }
    const int z = i - (512 * 128 + 128 * 64);
    if (z >= 0 && z < NBUCK) bcursor[z] = z * BCAP;
}

// ---------------------------------------------------------------------------
// GEMM1 (depth-4 pipeline, proven 249us config): sup0_bf16[N,128] =
// A_f32[N,512] @ W0 (Wt bf16). 4 waves (2m x 2n), tile 64x128, BK=32,
// 16 k-steps. Four named register prefetch slots (slot = t&3),
// double-buffered LDS, raw barriers (loads cross barriers).
// ---------------------------------------------------------------------------
__global__ __launch_bounds__(256) void gemm1_kernel(const float* __restrict__ A,
                                                    const unsigned short* __restrict__ Wt,
                                                    unsigned short* __restrict__ C, int N) {
    constexpr int K   = 512;
    constexpr int M   = 128;
    constexpr int LDT = 40;       // LDS row stride (ushorts)

    __shared__ __align__(16) unsigned short As[2][64 * LDT];
    __shared__ __align__(16) unsigned short Bs[2][M * LDT];

    const int tid  = threadIdx.x;
    const int lane = tid & 63;
    const int wid  = tid >> 6;
    const int wm   = wid >> 1;
    const int wn   = wid & 1;
    const int brow = blockIdx.x * 64;

    const int ar0 = tid >> 3, akq = tid & 7;
    const int ar1 = ar0 + 32;
    const bool v0 = (brow + ar0) < N;
    const bool v1 = (brow + ar1) < N;
    const float* ap0 = A + (size_t)(brow + ar0) * K + akq * 4;
    const float* ap1 = A + (size_t)(brow + ar1) * K + akq * 4;
    const int br0 = tid >> 2, bkq = tid & 3;
    const unsigned short* bp0 = Wt + (size_t)br0 * K + bkq * 8;
    const unsigned short* bp1 = Wt + (size_t)(br0 + 64) * K + bkq * 8;

    // ---- 4 named prefetch slots ----
    float4 A0a, A0b, A1a, A1b, A2a, A2b, A3a, A3b;
    uint4  B0a, B0b, B1a, B1b, B2a, B2b, B3a, B3b;

#define ISSUE(s, t) do {                                                          \
        const int ko = (t) * 32;                                                  \
        A##s##a = v0 ? *reinterpret_cast<const float4*>(ap0 + ko)                 \
                     : make_float4(0.f, 0.f, 0.f, 0.f);                           \
        A##s##b = v1 ? *reinterpret_cast<const float4*>(ap1 + ko)                 \
                     : make_float4(0.f, 0.f, 0.f, 0.f);                           \
        B##s##a = *reinterpret_cast<const uint4*>(bp0 + ko);                      \
        B##s##b = *reinterpret_cast<const uint4*>(bp1 + ko);                      \
    } while (0)

#define WLDS(s, buf) do {                                                         \
        *reinterpret_cast<uint2*>(&As[buf][ar0 * LDT + akq * 4]) = packbf4(A##s##a); \
        *reinterpret_cast<uint2*>(&As[buf][ar1 * LDT + akq * 4]) = packbf4(A##s##b); \
        *reinterpret_cast<uint4*>(&Bs[buf][br0 * LDT + bkq * 8]) = B##s##a;          \
        *reinterpret_cast<uint4*>(&Bs[buf][(br0 + 64) * LDT + bkq * 8]) = B##s##b;   \
    } while (0)

    f32x4 acc[2][4];
#pragma unroll
    for (int m = 0; m < 2; ++m)
#pragma unroll
        for (int n = 0; n < 4; ++n) acc[m][n] = (f32x4){0.f, 0.f, 0.f, 0.f};

    const int afo = (wm * 32 + (lane & 15)) * LDT + (lane >> 4) * 8;
    const int bfo = (wn * 64 + (lane & 15)) * LDT + (lane >> 4) * 8;

    auto step = [&](int buf) {
        bf16x8 af[2], bfr[4];
#pragma unroll
        for (int m = 0; m < 2; ++m)
            af[m] = *reinterpret_cast<const bf16x8*>(&As[buf][afo + m * 16 * LDT]);
#pragma unroll
        for (int n = 0; n < 4; ++n)
            bfr[n] = *reinterpret_cast<const bf16x8*>(&Bs[buf][bfo + n * 16 * LDT]);
#pragma unroll
        for (int m = 0; m < 2; ++m)
#pragma unroll
            for (int n = 0; n < 4; ++n)
                acc[m][n] = __builtin_amdgcn_mfma_f32_16x16x32_bf16(af[m], bfr[n], acc[m][n], 0, 0, 0);
    };

    // prologue: tiles 0..3 in flight; tile 0 -> LDS0
    ISSUE(0, 0); ISSUE(1, 1); ISSUE(2, 2); ISSUE(3, 3);
    WLDS(0, 0);
    block_barrier();

    // 16 k-steps, 4 per outer iteration; tile t lives in slot t&3, LDS t&1.
#pragma unroll
    for (int i = 0; i < 4; ++i) {
        const int t = 4 * i;
        if (t + 4 < 16) ISSUE(0, t + 4);
        step(0);
        WLDS(1, 1);
        block_barrier();
        if (t + 5 < 16) ISSUE(1, t + 5);
        step(1);
        WLDS(2, 0);
        block_barrier();
        if (t + 6 < 16) ISSUE(2, t + 6);
        step(0);
        WLDS(3, 1);
        block_barrier();
        if (t + 7 < 16) ISSUE(3, t + 7);
        step(1);
        if (t + 4 < 16) WLDS(0, 0);
        block_barrier();
    }
#undef ISSUE
#undef WLDS

    const int rb = brow + wm * 32 + ((lane >> 4) * 4);
    const int cb = wn * 64 + (lane & 15);
#pragma unroll
    for (int m = 0; m < 2; ++m)
#pragma unroll
        for (int n = 0; n < 4; ++n)
#pragma unroll
            for (int j = 0; j < 4; ++j) {
                const int r = rb + m * 16 + j;
                if (r < N) C[(size_t)r * M + cb + n * 16] = f2bf(acc[m][n][j]);
            }
}

// ---------------------------------------------------------------------------
// LDS-free GEMM2: sup1_bf16[N,64] = h_bf16[N,128] @ W1 (Wt[64][128] bf16).
// ---------------------------------------------------------------------------
__global__ __launch_bounds__(256) void gemm2_kernel(const unsigned short* __restrict__ Hb,
                                                    const unsigned short* __restrict__ Wt,
                                                    unsigned short* __restrict__ C) {
    const int gw = (blockIdx.x * 256 + threadIdx.x) >> 6;
    if (gw >= N_NODES / 16) return;
    const int lane = threadIdx.x & 63;
    const int rlo = lane & 15, khi = lane >> 4;
    const int rb = gw * 16;

    const unsigned short* wp = Wt + (size_t)rlo * 128 + khi * 8;
    bf16x8 b[4][4];
#pragma unroll
    for (int n = 0; n < 4; ++n)
#pragma unroll
        for (int t = 0; t < 4; ++t)
            b[n][t] = *reinterpret_cast<const bf16x8*>(wp + (size_t)n * 16 * 128 + t * 32);

    f32x4 acc[4];
#pragma unroll
    for (int n = 0; n < 4; ++n) acc[n] = (f32x4){0.f, 0.f, 0.f, 0.f};

    const unsigned short* hp = Hb + (size_t)(rb + rlo) * 128 + khi * 8;
#pragma unroll
    for (int t = 0; t < 4; ++t) {
        const bf16x8 af = *reinterpret_cast<const bf16x8*>(hp + t * 32);
#pragma unroll
        for (int n = 0; n < 4; ++n)
            acc[n] = __builtin_amdgcn_mfma_f32_16x16x32_bf16(af, b[n][t], acc[n], 0, 0, 0);
    }

#pragma unroll
    for (int n = 0; n < 4; ++n)
#pragma unroll
        for (int j = 0; j < 4; ++j)
            C[(size_t)(rb + khi * 4 + j) * 64 + n * 16 + rlo] = f2bf(acc[n][j]);
}

// ---------------------------------------------------------------------------
// Bucket append (block-aggregated): each thread caches its 16 edges in
// registers ONCE (rows read once, not twice); LDS histogram -> one global
// atomic per (block, nonzero bucket) -> append into fixed region [b*BCAP..).
// ---------------------------------------------------------------------------
#define SCAT_CH 4096
__global__ __launch_bounds__(256) void scatter_bucket_kernel(const int* __restrict__ rows,
                                                             const int* __restrict__ cols,
                                                             const float* __restrict__ vals,
                                                             int* __restrict__ bcursor,
                                                             int2* __restrict__ tmp) {
    __shared__ int hist[NBUCK];   // counts, then global-base cursors
    const int tid = threadIdx.x;
    const int e0  = blockIdx.x * SCAT_CH;

    // cache this thread's 16 edges in registers (all indices compile-time)
    int   er[16];
    int   ec[16];
    float ev[16];
#pragma unroll
    for (int i = 0; i < 16; ++i) {
        const int e = e0 + i * 256 + tid;
        const bool ok = e < N_EDGES;
        er[i] = ok ? rows[e] : -1;
        ec[i] = ok ? cols[e] : 0;
        ev[i] = ok ? vals[e] : 0.f;
    }

    for (int b = tid; b < NBUCK; b += 256) hist[b] = 0;
    __syncthreads();

    // phase 1: block-local histogram (from registers)
#pragma unroll
    for (int i = 0; i < 16; ++i)
        if (er[i] >= 0) atomicAdd(&hist[er[i] >> 7], 1);
    __syncthreads();

    // phase 2: reserve global region per bucket (one atomic per nonzero bucket)
    for (int b = tid; b < NBUCK; b += 256) {
        const int hcnt = hist[b];
        hist[b] = (hcnt > 0) ? atomicAdd(&bcursor[b], hcnt) : 0;
    }
    __syncthreads();

    // phase 3: append via LDS cursors (payload from registers)
#pragma unroll
    for (int i = 0; i < 16; ++i) {
        if (er[i] >= 0) {
            const int pos = atomicAdd(&hist[er[i] >> 7], 1);
            tmp[pos] = make_int2(ec[i] | ((er[i] & 127) << 17), __float_as_int(ev[i]));
        }
    }
}

// ---------------------------------------------------------------------------
// bucket_csr: one block per bucket. Edges cached in registers across the
// histogram and sort phases (tmp read ONCE). LDS int histogram, thread-0
// scan, row_range emit, row-sort into meta via LDS int cursors.
// ---------------------------------------------------------------------------
__global__ __launch_bounds__(256) void bucket_csr_kernel(const int* __restrict__ bcursor,
                                                         const int2* __restrict__ tmp,
                                                         int2* __restrict__ meta,
                                                         int2* __restrict__ row_range) {
    __shared__ int cnt_sh[128];
    __shared__ int startsh[128];
    __shared__ int cur[128];
    const int b   = blockIdx.x;
    const int tid = threadIdx.x;
    const int base = b * BCAP;
    const int cnt  = bcursor[b] - base;

    // cache this block's edges (<=16 per thread; masked lanes issue no loads)
    int2 w[16];
#pragma unroll
    for (int i = 0; i < 16; ++i) {
        const int j = i * 256 + tid;
        w[i] = (j < cnt) ? tmp[base + j] : make_int2(-1, 0);
    }

    if (tid < 128) cnt_sh[tid] = 0;
    __syncthreads();

#pragma unroll
    for (int i = 0; i < 16; ++i)
        if (w[i].x >= 0) atomicAdd(&cnt_sh[((unsigned int)w[i].x) >> 17], 1);
    __syncthreads();

    if (tid == 0) {
        int a = base;
        for (int i = 0; i < 128; ++i) { startsh[i] = a; a += cnt_sh[i]; }
    }
    __syncthreads();

    if (tid < 128) {
        cur[tid] = startsh[tid];
        const int row = (b << 7) + tid;
        if (row < N_NODES)
            row_range[row] = make_int2(startsh[tid], startsh[tid] + cnt_sh[tid]);
    }
    __syncthreads();

#pragma unroll
    for (int i = 0; i < 16; ++i) {
        if (w[i].x >= 0) {
            const int rl  = ((unsigned int)w[i].x) >> 17;
            const int pos = atomicAdd(&cur[rl], 1);
            meta[pos] = make_int2(w[i].x & 0x1FFFF, w[i].y);
        }
    }
}

// ---------------------------------------------------------------------------
// Atomic-free SpMM, one wave per row, NG edge-parallel groups, UN=2 unroll.
// ---------------------------------------------------------------------------
template<int DIM, bool RELU_BF16_OUT>
__global__ __launch_bounds__(256) void spmm_kernel(const int2* __restrict__ row_range,
                                                   const int2* __restrict__ meta,
                                                   const unsigned short* __restrict__ sup,
                                                   const float* __restrict__ bias,
                                                   void* __restrict__ aggv) {
    const int wv = (blockIdx.x * 256 + threadIdx.x) >> 6;  // row id
    if (wv >= N_NODES) return;
    const int lane = threadIdx.x & 63;

    constexpr int GL = DIM / 8;              // lanes per group (16 / 8)
    constexpr int NG = 64 / GL;              // edge-parallel groups (4 / 8)
    constexpr int UN = 2;                    // unroll depth
    const int grp = lane / GL;
    const int sub = lane % GL;

    const int2 rr = row_range[wv];
    const int start = rr.x, end = rr.y;

    float a[8] = {0.f, 0.f, 0.f, 0.f, 0.f, 0.f, 0.f, 0.f};

    int j = start + grp;
    while (j + (UN - 1) * NG < end) {
        int2 e[UN];
#pragma unroll
        for (int u = 0; u < UN; ++u) e[u] = meta[j + u * NG];
        bf16x8 s[UN];
#pragma unroll
        for (int u = 0; u < UN; ++u)
            s[u] = *reinterpret_cast<const bf16x8*>(sup + (size_t)e[u].x * DIM + sub * 8);
#pragma unroll
        for (int u = 0; u < UN; ++u) {
            const float v = __int_as_float(e[u].y);
#pragma unroll
            for (int d = 0; d < 8; ++d)
                a[d] = fmaf(v, bfu2f((unsigned short)s[u][d]), a[d]);
        }
        j += UN * NG;
    }
    for (; j < end; j += NG) {
        const int2 e = meta[j];
        const bf16x8 s = *reinterpret_cast<const bf16x8*>(sup + (size_t)e.x * DIM + sub * 8);
        const float v = __int_as_float(e.y);
#pragma unroll
        for (int d = 0; d < 8; ++d)
            a[d] = fmaf(v, bfu2f((unsigned short)s[d]), a[d]);
    }

#pragma unroll
    for (int d = 0; d < 8; ++d) {
        if (GL == 8) a[d] += __shfl_xor(a[d], 8);
        a[d] += __shfl_xor(a[d], 16);
        a[d] += __shfl_xor(a[d], 32);
    }

    if (lane < GL) {
        const float4 b0 = *reinterpret_cast<const float4*>(bias + sub * 8);
        const float4 b1 = *reinterpret_cast<const float4*>(bias + sub * 8 + 4);
        float o[8];
        o[0] = a[0] + b0.x; o[1] = a[1] + b0.y; o[2] = a[2] + b0.z; o[3] = a[3] + b0.w;
        o[4] = a[4] + b1.x; o[5] = a[5] + b1.y; o[6] = a[6] + b1.z; o[7] = a[7] + b1.w;
        if (RELU_BF16_OUT) {
            unsigned short* h = (unsigned short*)aggv;
            bf16x8 r;
#pragma unroll
            for (int d = 0; d < 8; ++d) r[d] = (short)f2bf(fmaxf(o[d], 0.f));
            *reinterpret_cast<bf16x8*>(h + (size_t)wv * DIM + sub * 8) = r;
        } else {
            float* og = (float*)aggv;
            float* dst = og + (size_t)wv * DIM + sub * 8;
            *reinterpret_cast<float4*>(dst)     = make_float4(o[0], o[1], o[2], o[3]);
            *reinterpret_cast<float4*>(dst + 4) = make_float4(o[4], o[5], o[6], o[7]);
        }
    }
}

// ---------------------------------------------------------------------------
extern "C" void kernel_launch(void* const* d_in, const int* in_sizes, int n_in,
                              void* d_out, int out_size, void* d_ws, size_t ws_size,
                              hipStream_t stream) {
    const float* x    = (const float*)d_in[0];
    const int*   rows = (const int*)d_in[1];
    const int*   cols = (const int*)d_in[2];
    const float* vals = (const float*)d_in[3];
    const float* W0   = (const float*)d_in[4];
    const float* b0   = (const float*)d_in[5];
    const float* W1   = (const float*)d_in[6];
    const float* b1   = (const float*)d_in[7];
    float*       out  = (float*)d_out;

    // Workspace carve (all chunks 16B-multiple)
    char* p = (char*)d_ws;
    unsigned short* sup0 = (unsigned short*)p;  p += (size_t)N_NODES * 128 * 2;  // 25.6 MB
    unsigned short* h    = (unsigned short*)p;  p += (size_t)N_NODES * 128 * 2;  // 25.6 MB
    unsigned short* sup1 = (unsigned short*)p;  p += (size_t)N_NODES * 64 * 2;   // 12.8 MB
    unsigned short* W0t  = (unsigned short*)p;  p += (size_t)512 * 128 * 2;
    unsigned short* W1t  = (unsigned short*)p;  p += (size_t)128 * 64 * 2;
    int*   bcursor  = (int*)p;                  p += (size_t)((NBUCK + 3) / 4) * 16;
    int2*  row_range= (int2*)p;                 p += (size_t)N_NODES * 8;        // 0.8 MB
    int2*  tmp      = (int2*)p;                 p += (size_t)NBUCK * BCAP * 8;   // 25.6 MB
    int2*  meta     = (int2*)p;                 p += (size_t)NBUCK * BCAP * 8;   // 25.6 MB

    const int prep_blocks = (512 * 128 + 128 * 64 + NBUCK + 255) / 256;  // 292
    const int scat_blocks = (N_EDGES + SCAT_CH - 1) / SCAT_CH;           // 391
    const int gemm_blocks = (N_NODES + 63) / 64;                         // 1563
    const int gem2_blocks = (N_NODES / 16 + 3) / 4;                      // 1563
    const int spmm_blocks = (N_NODES * 64 + 255) / 256;                  // 25000

    // ---- prep (W converts + bucket cursor init) ----
    prep_kernel<<<prep_blocks, 256, 0, stream>>>(W0, W1, W0t, W1t, bcursor);

    // ---- edge reorg: bucket append + per-bucket CSR finish ----
    scatter_bucket_kernel<<<scat_blocks, 256, 0, stream>>>(rows, cols, vals, bcursor, tmp);
    bucket_csr_kernel<<<NBUCK, 256, 0, stream>>>(bcursor, tmp, meta, row_range);

    // ---- Layer 0 ----
    gemm1_kernel<<<gemm_blocks, 256, 0, stream>>>(x, W0t, sup0, N_NODES);
    spmm_kernel<128, true><<<spmm_blocks, 256, 0, stream>>>(row_range, meta, sup0, b0, h);

    // ---- Layer 1 ----
    gemm2_kernel<<<gem2_blocks, 256, 0, stream>>>(h, W1t, sup1);
    spmm_kernel<64, false><<<spmm_blocks, 256, 0, stream>>>(row_range, meta, sup1, b1, out);
}

// Round 15
// 218.719 us; speedup vs baseline: 1.2563x; 1.0260x over previous
//
#include <hip/hip_runtime.h>

#define N_NODES 100000
#define N_EDGES 1600000
#define NBUCK   ((N_NODES + 127) / 128)   // 782 buckets of 128 rows
#define BCAP    4096                      // fixed bucket capacity (mean 2048, std ~45)
// IN_DIM=512, HID_DIM=128, OUT_DIM=64

typedef __attribute__((ext_vector_type(8))) short bf16x8;
typedef __attribute__((ext_vector_type(4))) float f32x4;

__device__ __forceinline__ unsigned short f2bf(float f) {
    unsigned int u = __builtin_bit_cast(unsigned int, f);
    u = (u + 0x7FFFu + ((u >> 16) & 1u)) >> 16;   // RNE
    return (unsigned short)u;
}
__device__ __forceinline__ float bfu2f(unsigned short u) {
    return __builtin_bit_cast(float, (unsigned int)u << 16);
}
__device__ __forceinline__ uint2 packbf4(float4 v) {
    uint2 p;
    p.x = (unsigned int)f2bf(v.x) | ((unsigned int)f2bf(v.y) << 16);
    p.y = (unsigned int)f2bf(v.z) | ((unsigned int)f2bf(v.w) << 16);
    return p;
}

// Raw barrier: waits LDS ops only — global prefetch loads stay in flight.
__device__ __forceinline__ void block_barrier() {
    asm volatile("s_waitcnt lgkmcnt(0)" ::: "memory");
    __builtin_amdgcn_sched_barrier(0);
    __builtin_amdgcn_s_barrier();
    __builtin_amdgcn_sched_barrier(0);
}

// ---------------------------------------------------------------------------
// prep: W0->W0t bf16 transposed, W1->W1t bf16 transposed,
// bcursor[b] = b*BCAP (fixed bucket bases).
// ---------------------------------------------------------------------------
__global__ __launch_bounds__(256) void prep_kernel(const float* __restrict__ W0,
                                                   const float* __restrict__ W1,
                                                   unsigned short* __restrict__ W0t,
                                                   unsigned short* __restrict__ W1t,
                                                   int* __restrict__ bcursor) {
    const int i = blockIdx.x * 256 + threadIdx.x;
    if (i < 512 * 128) {
        const int k = i / 128, c = i % 128;
        W0t[c * 512 + k] = f2bf(W0[i]);
    }
    const int j = i - 512 * 128;
    if (j >= 0 && j < 128 * 64) {
        const int k = j / 64, c = j % 64;
        W1t[c * 128 + k] = f2bf(W1[j]);
    }
    const int z = i - (512 * 128 + 128 * 64);
    if (z >= 0 && z < NBUCK) bcursor[z] = z * BCAP;
}

// ---------------------------------------------------------------------------
// GEMM1 (depth-4 pipeline, proven config): sup0_bf16[N,128] =
// A_f32[N,512] @ W0 (Wt bf16). 4 waves (2m x 2n), tile 64x128, BK=32,
// 16 k-steps. Four named register prefetch slots (slot = t&3),
// double-buffered LDS, raw barriers (loads cross barriers).
// ---------------------------------------------------------------------------
__global__ __launch_bounds__(256) void gemm1_kernel(const float* __restrict__ A,
                                                    const unsigned short* __restrict__ Wt,
                                                    unsigned short* __restrict__ C, int N) {
    constexpr int K   = 512;
    constexpr int M   = 128;
    constexpr int LDT = 40;       // LDS row stride (ushorts)

    __shared__ __align__(16) unsigned short As[2][64 * LDT];
    __shared__ __align__(16) unsigned short Bs[2][M * LDT];

    const int tid  = threadIdx.x;
    const int lane = tid & 63;
    const int wid  = tid >> 6;
    const int wm   = wid >> 1;
    const int wn   = wid & 1;
    const int brow = blockIdx.x * 64;

    const int ar0 = tid >> 3, akq = tid & 7;
    const int ar1 = ar0 + 32;
    const bool v0 = (brow + ar0) < N;
    const bool v1 = (brow + ar1) < N;
    const float* ap0 = A + (size_t)(brow + ar0) * K + akq * 4;
    const float* ap1 = A + (size_t)(brow + ar1) * K + akq * 4;
    const int br0 = tid >> 2, bkq = tid & 3;
    const unsigned short* bp0 = Wt + (size_t)br0 * K + bkq * 8;
    const unsigned short* bp1 = Wt + (size_t)(br0 + 64) * K + bkq * 8;

    // ---- 4 named prefetch slots ----
    float4 A0a, A0b, A1a, A1b, A2a, A2b, A3a, A3b;
    uint4  B0a, B0b, B1a, B1b, B2a, B2b, B3a, B3b;

#define ISSUE(s, t) do {                                                          \
        const int ko = (t) * 32;                                                  \
        A##s##a = v0 ? *reinterpret_cast<const float4*>(ap0 + ko)                 \
                     : make_float4(0.f, 0.f, 0.f, 0.f);                           \
        A##s##b = v1 ? *reinterpret_cast<const float4*>(ap1 + ko)                 \
                     : make_float4(0.f, 0.f, 0.f, 0.f);                           \
        B##s##a = *reinterpret_cast<const uint4*>(bp0 + ko);                      \
        B##s##b = *reinterpret_cast<const uint4*>(bp1 + ko);                      \
    } while (0)

#define WLDS(s, buf) do {                                                         \
        *reinterpret_cast<uint2*>(&As[buf][ar0 * LDT + akq * 4]) = packbf4(A##s##a); \
        *reinterpret_cast<uint2*>(&As[buf][ar1 * LDT + akq * 4]) = packbf4(A##s##b); \
        *reinterpret_cast<uint4*>(&Bs[buf][br0 * LDT + bkq * 8]) = B##s##a;          \
        *reinterpret_cast<uint4*>(&Bs[buf][(br0 + 64) * LDT + bkq * 8]) = B##s##b;   \
    } while (0)

    f32x4 acc[2][4];
#pragma unroll
    for (int m = 0; m < 2; ++m)
#pragma unroll
        for (int n = 0; n < 4; ++n) acc[m][n] = (f32x4){0.f, 0.f, 0.f, 0.f};

    const int afo = (wm * 32 + (lane & 15)) * LDT + (lane >> 4) * 8;
    const int bfo = (wn * 64 + (lane & 15)) * LDT + (lane >> 4) * 8;

    auto step = [&](int buf) {
        bf16x8 af[2], bfr[4];
#pragma unroll
        for (int m = 0; m < 2; ++m)
            af[m] = *reinterpret_cast<const bf16x8*>(&As[buf][afo + m * 16 * LDT]);
#pragma unroll
        for (int n = 0; n < 4; ++n)
            bfr[n] = *reinterpret_cast<const bf16x8*>(&Bs[buf][bfo + n * 16 * LDT]);
#pragma unroll
        for (int m = 0; m < 2; ++m)
#pragma unroll
            for (int n = 0; n < 4; ++n)
                acc[m][n] = __builtin_amdgcn_mfma_f32_16x16x32_bf16(af[m], bfr[n], acc[m][n], 0, 0, 0);
    };

    // prologue: tiles 0..3 in flight; tile 0 -> LDS0
    ISSUE(0, 0); ISSUE(1, 1); ISSUE(2, 2); ISSUE(3, 3);
    WLDS(0, 0);
    block_barrier();

    // 16 k-steps, 4 per outer iteration; tile t lives in slot t&3, LDS t&1.
#pragma unroll
    for (int i = 0; i < 4; ++i) {
        const int t = 4 * i;
        if (t + 4 < 16) ISSUE(0, t + 4);
        step(0);
        WLDS(1, 1);
        block_barrier();
        if (t + 5 < 16) ISSUE(1, t + 5);
        step(1);
        WLDS(2, 0);
        block_barrier();
        if (t + 6 < 16) ISSUE(2, t + 6);
        step(0);
        WLDS(3, 1);
        block_barrier();
        if (t + 7 < 16) ISSUE(3, t + 7);
        step(1);
        if (t + 4 < 16) WLDS(0, 0);
        block_barrier();
    }
#undef ISSUE
#undef WLDS

    const int rb = brow + wm * 32 + ((lane >> 4) * 4);
    const int cb = wn * 64 + (lane & 15);
#pragma unroll
    for (int m = 0; m < 2; ++m)
#pragma unroll
        for (int n = 0; n < 4; ++n)
#pragma unroll
            for (int j = 0; j < 4; ++j) {
                const int r = rb + m * 16 + j;
                if (r < N) C[(size_t)r * M + cb + n * 16] = f2bf(acc[m][n][j]);
            }
}

// ---------------------------------------------------------------------------
// LDS-free GEMM2: sup1_bf16[N,64] = h_bf16[N,128] @ W1 (Wt[64][128] bf16).
// ---------------------------------------------------------------------------
__global__ __launch_bounds__(256) void gemm2_kernel(const unsigned short* __restrict__ Hb,
                                                    const unsigned short* __restrict__ Wt,
                                                    unsigned short* __restrict__ C) {
    const int gw = (blockIdx.x * 256 + threadIdx.x) >> 6;
    if (gw >= N_NODES / 16) return;
    const int lane = threadIdx.x & 63;
    const int rlo = lane & 15, khi = lane >> 4;
    const int rb = gw * 16;

    const unsigned short* wp = Wt + (size_t)rlo * 128 + khi * 8;
    bf16x8 b[4][4];
#pragma unroll
    for (int n = 0; n < 4; ++n)
#pragma unroll
        for (int t = 0; t < 4; ++t)
            b[n][t] = *reinterpret_cast<const bf16x8*>(wp + (size_t)n * 16 * 128 + t * 32);

    f32x4 acc[4];
#pragma unroll
    for (int n = 0; n < 4; ++n) acc[n] = (f32x4){0.f, 0.f, 0.f, 0.f};

    const unsigned short* hp = Hb + (size_t)(rb + rlo) * 128 + khi * 8;
#pragma unroll
    for (int t = 0; t < 4; ++t) {
        const bf16x8 af = *reinterpret_cast<const bf16x8*>(hp + t * 32);
#pragma unroll
        for (int n = 0; n < 4; ++n)
            acc[n] = __builtin_amdgcn_mfma_f32_16x16x32_bf16(af, b[n][t], acc[n], 0, 0, 0);
    }

#pragma unroll
    for (int n = 0; n < 4; ++n)
#pragma unroll
        for (int j = 0; j < 4; ++j)
            C[(size_t)(rb + khi * 4 + j) * 64 + n * 16 + rlo] = f2bf(acc[n][j]);
}

// ---------------------------------------------------------------------------
// Bucket append (block-aggregated): each thread caches its 16 edges in
// registers ONCE; LDS histogram -> one global atomic per (block, nonzero
// bucket) -> append into fixed region [b*BCAP..).
// ---------------------------------------------------------------------------
#define SCAT_CH 4096
__global__ __launch_bounds__(256) void scatter_bucket_kernel(const int* __restrict__ rows,
                                                             const int* __restrict__ cols,
                                                             const float* __restrict__ vals,
                                                             int* __restrict__ bcursor,
                                                             int2* __restrict__ tmp) {
    __shared__ int hist[NBUCK];   // counts, then global-base cursors
    const int tid = threadIdx.x;
    const int e0  = blockIdx.x * SCAT_CH;

    // cache this thread's 16 edges in registers (all indices compile-time)
    int   er[16];
    int   ec[16];
    float ev[16];
#pragma unroll
    for (int i = 0; i < 16; ++i) {
        const int e = e0 + i * 256 + tid;
        const bool ok = e < N_EDGES;
        er[i] = ok ? rows[e] : -1;
        ec[i] = ok ? cols[e] : 0;
        ev[i] = ok ? vals[e] : 0.f;
    }

    for (int b = tid; b < NBUCK; b += 256) hist[b] = 0;
    __syncthreads();

    // phase 1: block-local histogram (from registers)
#pragma unroll
    for (int i = 0; i < 16; ++i)
        if (er[i] >= 0) atomicAdd(&hist[er[i] >> 7], 1);
    __syncthreads();

    // phase 2: reserve global region per bucket (one atomic per nonzero bucket)
    for (int b = tid; b < NBUCK; b += 256) {
        const int hcnt = hist[b];
        hist[b] = (hcnt > 0) ? atomicAdd(&bcursor[b], hcnt) : 0;
    }
    __syncthreads();

    // phase 3: append via LDS cursors (payload from registers)
#pragma unroll
    for (int i = 0; i < 16; ++i) {
        if (er[i] >= 0) {
            const int pos = atomicAdd(&hist[er[i] >> 7], 1);
            tmp[pos] = make_int2(ec[i] | ((er[i] & 127) << 17), __float_as_int(ev[i]));
        }
    }
}

// ---------------------------------------------------------------------------
// Fused bucket SpMM: one 512-thread block per bucket. Loads the bucket's
// edges into registers, row-sorts them into a 32KB LDS array (int LDS
// histogram -> thread-0 scan -> LDS-cursor scatter — the proven bucket_csr
// logic, now block-local), then 8 waves x 16 rows run the proven
// edge-group gather with edge meta broadcast from LDS. No meta/row_range
// globals, no separate CSR-finish kernel.
// ---------------------------------------------------------------------------
template<int DIM, bool RELU_BF16_OUT>
__global__ __launch_bounds__(512) void spmm_bucket_kernel(const int* __restrict__ bcursor,
                                                          const int2* __restrict__ tmp,
                                                          const unsigned short* __restrict__ sup,
                                                          const float* __restrict__ bias,
                                                          void* __restrict__ aggv) {
    constexpr int GL = DIM / 8;              // lanes per edge-group (16 / 8)
    constexpr int NG = 64 / GL;              // edge-parallel groups per wave (4 / 8)

    __shared__ int2 eds[BCAP];               // 32 KB sorted edge array
    __shared__ int  cnt_sh[128];
    __shared__ int  startsh[128];
    __shared__ int  cur[128];

    const int b    = blockIdx.x;
    const int tid  = threadIdx.x;
    const int base = b * BCAP;
    const int cnt  = bcursor[b] - base;

    // ---- load edges to registers (8/thread) + histogram local rows ----
    int2 w[8];
#pragma unroll
    for (int i = 0; i < 8; ++i) {
        const int j = i * 512 + tid;
        w[i] = (j < cnt) ? tmp[base + j] : make_int2(-1, 0);
    }
    if (tid < 128) cnt_sh[tid] = 0;
    __syncthreads();
#pragma unroll
    for (int i = 0; i < 8; ++i)
        if (w[i].x >= 0) atomicAdd(&cnt_sh[((unsigned int)w[i].x) >> 17], 1);
    __syncthreads();

    if (tid == 0) {
        int a = 0;
        for (int i = 0; i < 128; ++i) { startsh[i] = a; a += cnt_sh[i]; }
    }
    __syncthreads();
    if (tid < 128) cur[tid] = startsh[tid];
    __syncthreads();

    // ---- row-sort into LDS ----
#pragma unroll
    for (int i = 0; i < 8; ++i) {
        if (w[i].x >= 0) {
            const int rl  = ((unsigned int)w[i].x) >> 17;
            const int pos = atomicAdd(&cur[rl], 1);
            eds[pos] = make_int2(w[i].x & 0x1FFFF, w[i].y);
        }
    }
    __syncthreads();

    // ---- per-row gather-reduce: 8 waves x 16 rows ----
    const int lane = tid & 63;
    const int wid  = tid >> 6;
    const int grp  = lane / GL;
    const int sub  = lane % GL;

    for (int r8 = 0; r8 < 16; ++r8) {
        const int rl  = wid * 16 + r8;
        const int row = (b << 7) + rl;
        const int start = startsh[rl];
        const int end   = start + cnt_sh[rl];

        float a[8] = {0.f, 0.f, 0.f, 0.f, 0.f, 0.f, 0.f, 0.f};

        int j = start + grp;
        while (j + NG < end) {        // 2-deep unroll (UN*NG <= mean degree)
            const int2 e0 = eds[j];
            const int2 e1 = eds[j + NG];
            const bf16x8 s0 = *reinterpret_cast<const bf16x8*>(sup + (size_t)e0.x * DIM + sub * 8);
            const bf16x8 s1 = *reinterpret_cast<const bf16x8*>(sup + (size_t)e1.x * DIM + sub * 8);
            const float v0 = __int_as_float(e0.y);
            const float v1 = __int_as_float(e1.y);
#pragma unroll
            for (int d = 0; d < 8; ++d) a[d] = fmaf(v0, bfu2f((unsigned short)s0[d]), a[d]);
#pragma unroll
            for (int d = 0; d < 8; ++d) a[d] = fmaf(v1, bfu2f((unsigned short)s1[d]), a[d]);
            j += 2 * NG;
        }
        for (; j < end; j += NG) {
            const int2 e = eds[j];
            const bf16x8 s = *reinterpret_cast<const bf16x8*>(sup + (size_t)e.x * DIM + sub * 8);
            const float v = __int_as_float(e.y);
#pragma unroll
            for (int d = 0; d < 8; ++d) a[d] = fmaf(v, bfu2f((unsigned short)s[d]), a[d]);
        }

        // cross-group reduction
#pragma unroll
        for (int d = 0; d < 8; ++d) {
            if (GL == 8) a[d] += __shfl_xor(a[d], 8);
            a[d] += __shfl_xor(a[d], 16);
            a[d] += __shfl_xor(a[d], 32);
        }

        if (lane < GL && row < N_NODES) {
            const float4 b0 = *reinterpret_cast<const float4*>(bias + sub * 8);
            const float4 b1 = *reinterpret_cast<const float4*>(bias + sub * 8 + 4);
            float o[8];
            o[0] = a[0] + b0.x; o[1] = a[1] + b0.y; o[2] = a[2] + b0.z; o[3] = a[3] + b0.w;
            o[4] = a[4] + b1.x; o[5] = a[5] + b1.y; o[6] = a[6] + b1.z; o[7] = a[7] + b1.w;
            if (RELU_BF16_OUT) {
                unsigned short* hb = (unsigned short*)aggv;
                bf16x8 r;
#pragma unroll
                for (int d = 0; d < 8; ++d) r[d] = (short)f2bf(fmaxf(o[d], 0.f));
                *reinterpret_cast<bf16x8*>(hb + (size_t)row * DIM + sub * 8) = r;
            } else {
                float* og = (float*)aggv;
                float* dst = og + (size_t)row * DIM + sub * 8;
                *reinterpret_cast<float4*>(dst)     = make_float4(o[0], o[1], o[2], o[3]);
                *reinterpret_cast<float4*>(dst + 4) = make_float4(o[4], o[5], o[6], o[7]);
            }
        }
    }
}

// ---------------------------------------------------------------------------
extern "C" void kernel_launch(void* const* d_in, const int* in_sizes, int n_in,
                              void* d_out, int out_size, void* d_ws, size_t ws_size,
                              hipStream_t stream) {
    const float* x    = (const float*)d_in[0];
    const int*   rows = (const int*)d_in[1];
    const int*   cols = (const int*)d_in[2];
    const float* vals = (const float*)d_in[3];
    const float* W0   = (const float*)d_in[4];
    const float* b0   = (const float*)d_in[5];
    const float* W1   = (const float*)d_in[6];
    const float* b1   = (const float*)d_in[7];
    float*       out  = (float*)d_out;

    // Workspace carve (all chunks 16B-multiple)
    char* p = (char*)d_ws;
    unsigned short* sup0 = (unsigned short*)p;  p += (size_t)N_NODES * 128 * 2;  // 25.6 MB
    unsigned short* h    = (unsigned short*)p;  p += (size_t)N_NODES * 128 * 2;  // 25.6 MB
    unsigned short* sup1 = (unsigned short*)p;  p += (size_t)N_NODES * 64 * 2;   // 12.8 MB
    unsigned short* W0t  = (unsigned short*)p;  p += (size_t)512 * 128 * 2;
    unsigned short* W1t  = (unsigned short*)p;  p += (size_t)128 * 64 * 2;
    int*   bcursor  = (int*)p;                  p += (size_t)((NBUCK + 3) / 4) * 16;
    int2*  tmp      = (int2*)p;                 p += (size_t)NBUCK * BCAP * 8;   // 25.6 MB

    const int prep_blocks = (512 * 128 + 128 * 64 + NBUCK + 255) / 256;  // 292
    const int scat_blocks = (N_EDGES + SCAT_CH - 1) / SCAT_CH;           // 391
    const int gemm_blocks = (N_NODES + 63) / 64;                         // 1563
    const int gem2_blocks = (N_NODES / 16 + 3) / 4;                      // 1563

    // ---- prep (W converts + bucket cursor init) ----
    prep_kernel<<<prep_blocks, 256, 0, stream>>>(W0, W1, W0t, W1t, bcursor);

    // ---- edge reorg: bucket append (CSR finish fused into spmm) ----
    scatter_bucket_kernel<<<scat_blocks, 256, 0, stream>>>(rows, cols, vals, bcursor, tmp);

    // ---- Layer 0 ----
    gemm1_kernel<<<gemm_blocks, 256, 0, stream>>>(x, W0t, sup0, N_NODES);
    spmm_bucket_kernel<128, true><<<NBUCK, 512, 0, stream>>>(bcursor, tmp, sup0, b0, h);

    // ---- Layer 1 ----
    gemm2_kernel<<<gem2_blocks, 256, 0, stream>>>(h, W1t, sup1);
    spmm_bucket_kernel<64, false><<<NBUCK, 512, 0, stream>>>(bcursor, tmp, sup1, b1, out);
}